// Round 2
// baseline (2838.396 us; speedup 1.0000x reference)
//
#include <hip/hip_runtime.h>

#define HW    4096      // H*W
#define NC    64        // channels / latent dim
#define NK    1024      // codebook entries
#define NB    32        // batch
#define NPIX  (NB*HW)   // 131072 pixels
#define TOTAL (NPIX*NC) // 8388608 output elements of z_q

// Margin for the fp32 fast path. Worst-case fp32 score error is ~2e-4
// (16-deep fmaf chains on values ~O(100)); 1e-2 gives ~50x safety.
// Pixels whose top-2 gap is below this get an exact fp64 rescan.
#define AMBIG_MARGIN 1e-2f

// Prologue: per-code squared norms into d_ws, and zero the loss accumulator.
__global__ void vq_cnorm_kernel(const float* __restrict__ cb,
                                float* __restrict__ cnorm,
                                float* __restrict__ loss_out) {
    int k = blockIdx.x * blockDim.x + threadIdx.x;
    if (k == 0) loss_out[0] = 0.0f;
    if (k < NK) {
        // fp64 accumulate, round once -> cnorm error ~1 ulp of fp32
        double s = 0.0;
        #pragma unroll
        for (int c = 0; c < NC; ++c) {
            double v = (double)cb[k * NC + c];
            s = fma(v, v, s);
        }
        cnorm[k] = (float)s;
    }
}

// Main: one thread per pixel. z vector in VGPRs; codebook scanned with
// wave-uniform indices; argmin over score = ||e||^2 - 2 z.e (the ||z||^2
// term is per-pixel constant -> argmin unchanged). Ambiguous pixels
// (top-2 gap < AMBIG_MARGIN) are rescanned exactly in fp64.
__global__ __launch_bounds__(256) void vq_argmin_kernel(
        const float* __restrict__ z,
        const float* __restrict__ cb,
        const float* __restrict__ cnorm,
        float* __restrict__ zq,
        float* __restrict__ loss_out) {
    const int g = blockIdx.x * 256 + threadIdx.x;   // global pixel id
    const int b = g >> 12;                          // g / 4096
    const int p = g & 4095;                         // g % 4096
    const size_t base = (size_t)b * (NC * HW) + p;

    // Load this pixel's 64 channels into registers (coalesced per channel).
    float zreg[NC];
    #pragma unroll
    for (int c = 0; c < NC; ++c) zreg[c] = z[base + (size_t)c * HW];

    float best = 3.4e38f, best2 = 3.4e38f;
    int bidx = 0;
    for (int k = 0; k < NK; ++k) {
        const float* __restrict__ e = cb + k * NC;  // wave-uniform address
        float d0 = 0.f, d1 = 0.f, d2 = 0.f, d3 = 0.f;
        #pragma unroll
        for (int c = 0; c < NC; c += 4) {
            d0 = fmaf(zreg[c + 0], e[c + 0], d0);
            d1 = fmaf(zreg[c + 1], e[c + 1], d1);
            d2 = fmaf(zreg[c + 2], e[c + 2], d2);
            d3 = fmaf(zreg[c + 3], e[c + 3], d3);
        }
        float dot = (d0 + d1) + (d2 + d3);
        float score = fmaf(-2.0f, dot, cnorm[k]);
        if (score < best) {                // strict <: first min wins (jnp.argmin)
            best2 = best; best = score; bidx = k;
        } else if (score < best2) {
            best2 = score;
        }
    }

    // Slow path: top-2 too close for fp32 to be trusted -> exact fp64 rescan.
    if (best2 - best < AMBIG_MARGIN) {
        double dbest = 1.0e300;
        int di = 0;
        for (int k = 0; k < NK; ++k) {
            const float* __restrict__ e = cb + k * NC;
            double s0 = 0.0, s1 = 0.0, s2 = 0.0, s3 = 0.0;
            #pragma unroll
            for (int c = 0; c < NC; c += 4) {
                double t0 = (double)zreg[c + 0] - (double)e[c + 0];
                double t1 = (double)zreg[c + 1] - (double)e[c + 1];
                double t2 = (double)zreg[c + 2] - (double)e[c + 2];
                double t3 = (double)zreg[c + 3] - (double)e[c + 3];
                s0 = fma(t0, t0, s0);
                s1 = fma(t1, t1, s1);
                s2 = fma(t2, t2, s2);
                s3 = fma(t3, t3, s3);
            }
            double d2s = (s0 + s1) + (s2 + s3);
            if (d2s < dbest) { dbest = d2s; di = k; }
        }
        bidx = di;
    }

    // Gather winning code row -> z_q, accumulate squared error for the loss.
    float sse = 0.0f;
    const float* __restrict__ e = cb + bidx * NC;   // per-lane (divergent) row
    #pragma unroll
    for (int c = 0; c < NC; ++c) {
        float q = e[c];
        zq[base + (size_t)c * HW] = q;              // coalesced across lanes per c
        float d = q - zreg[c];
        sse = fmaf(d, d, sse);
    }

    // Block reduction of sse -> one atomicAdd per block.
    __shared__ float red[4];
    #pragma unroll
    for (int off = 32; off > 0; off >>= 1)
        sse += __shfl_down(sse, off);               // 64-lane wave reduce
    const int lane = threadIdx.x & 63;
    const int wid  = threadIdx.x >> 6;
    if (lane == 0) red[wid] = sse;
    __syncthreads();
    if (threadIdx.x == 0) {
        float bs = red[0] + red[1] + red[2] + red[3];
        // loss = (1 + BETA) * SSE / TOTAL, BETA = 0.25
        atomicAdd(loss_out, bs * (1.25f / (float)TOTAL));
    }
}

extern "C" void kernel_launch(void* const* d_in, const int* in_sizes, int n_in,
                              void* d_out, int out_size, void* d_ws, size_t ws_size,
                              hipStream_t stream) {
    const float* z  = (const float*)d_in[0];   // [32, 64, 64, 64] fp32
    const float* cb = (const float*)d_in[1];   // [1024, 64] fp32
    float* out      = (float*)d_out;           // z_q (8388608 floats) ++ loss (1 float)
    float* zq       = out;
    float* loss_out = out + TOTAL;
    float* cnorm    = (float*)d_ws;            // 1024 floats of scratch

    vq_cnorm_kernel<<<(NK + 255) / 256, 256, 0, stream>>>(cb, cnorm, loss_out);
    vq_argmin_kernel<<<NPIX / 256, 256, 0, stream>>>(z, cb, cnorm, zq, loss_out);
}

// Round 3
// 924.578 us; speedup vs baseline: 3.0699x; 3.0699x over previous
//
#include <hip/hip_runtime.h>

#define HW    4096      // H*W
#define NC    64        // channels / latent dim
#define NK    1024      // codebook entries
#define NB    32        // batch
#define NPIX  (NB*HW)   // 131072 pixels
#define TOTAL (NPIX*NC) // 8388608 output elements of z_q

// fp32 score error bound ~1.2e-4 (16-deep fmaf chains, partials O(32));
// margin 2e-3 gives ~16x safety. gap2 < margin -> exact fp64 top-2 compare;
// gap3 < margin (never in practice) -> exact fp64 full rescan.
#define MARGIN 2e-3f

// Prologue: per-code squared norms (fp64-accumulated) + zero loss slot.
__global__ void vq_cnorm_kernel(const float* __restrict__ cb,
                                float* __restrict__ cnorm,
                                float* __restrict__ loss_out) {
    int k = blockIdx.x * blockDim.x + threadIdx.x;
    if (k == 0) loss_out[0] = 0.0f;
    if (k < NK) {
        double s = 0.0;
        #pragma unroll
        for (int c = 0; c < NC; ++c) {
            double v = (double)cb[k * NC + c];
            s = fma(v, v, s);
        }
        cnorm[k] = (float)s;
    }
}

// Exact fp64 squared distance between register-resident z and one codebook row.
__device__ __forceinline__ double dist2_f64(const float* zr,
                                            const float4* __restrict__ row) {
    double s0 = 0.0, s1 = 0.0, s2 = 0.0, s3 = 0.0;
    #pragma unroll
    for (int j = 0; j < 16; ++j) {
        float4 e = row[j];
        double t0 = (double)zr[4 * j + 0] - (double)e.x;
        double t1 = (double)zr[4 * j + 1] - (double)e.y;
        double t2 = (double)zr[4 * j + 2] - (double)e.z;
        double t3 = (double)zr[4 * j + 3] - (double)e.w;
        s0 = fma(t0, t0, s0);
        s1 = fma(t1, t1, s1);
        s2 = fma(t2, t2, s2);
        s3 = fma(t3, t3, s3);
    }
    return (s0 + s1) + (s2 + s3);
}

// Main: one thread per pixel; z in 64 VGPRs; codebook rows streamed through
// two register buffers (prefetch distance 1 code) so 16 dwordx4 loads stay
// in flight instead of serializing on a starved register budget.
__global__ __launch_bounds__(256, 2) void vq_argmin_kernel(
        const float* __restrict__ z,
        const float* __restrict__ cb,
        const float* __restrict__ cnorm,
        float* __restrict__ zq,
        float* __restrict__ loss_out) {
    const int g = blockIdx.x * 256 + threadIdx.x;   // global pixel id
    const int b = g >> 12;                          // g / 4096
    const int p = g & 4095;                         // g % 4096
    const size_t base = (size_t)b * (NC * HW) + p;

    // Load this pixel's 64 channels into registers (coalesced per channel).
    float zreg[NC];
    #pragma unroll
    for (int c = 0; c < NC; ++c) zreg[c] = z[base + (size_t)c * HW];

    const float4* __restrict__ cb4 = (const float4*)cb;  // row k = cb4[16k..16k+15]

    float best = 3.4e38f, best2 = 3.4e38f, best3 = 3.4e38f;
    int bidx = 0, b2idx = 0;

#define SCORE_UPDATE(BUF, CN, K)                                         \
    {                                                                    \
        float d0 = 0.f, d1 = 0.f, d2 = 0.f, d3 = 0.f;                    \
        _Pragma("unroll")                                                \
        for (int j = 0; j < 16; ++j) {                                   \
            d0 = fmaf(zreg[4 * j + 0], BUF[j].x, d0);                    \
            d1 = fmaf(zreg[4 * j + 1], BUF[j].y, d1);                    \
            d2 = fmaf(zreg[4 * j + 2], BUF[j].z, d2);                    \
            d3 = fmaf(zreg[4 * j + 3], BUF[j].w, d3);                    \
        }                                                                \
        float dot = (d0 + d1) + (d2 + d3);                               \
        float s = fmaf(-2.0f, dot, CN);                                  \
        if (s < best)       { best3 = best2; best2 = best; b2idx = bidx; \
                              best = s; bidx = (K); }                    \
        else if (s < best2) { best3 = best2; best2 = s; b2idx = (K); }   \
        else                { best3 = fminf(best3, s); }                 \
    }

    float4 bufA[16], bufB[16];
    #pragma unroll
    for (int j = 0; j < 16; ++j) bufA[j] = cb4[j];      // code 0
    float cnA = cnorm[0], cnB;

    #pragma unroll 1
    for (int k = 0; k < NK; k += 2) {
        // prefetch code k+1 while code k computes
        #pragma unroll
        for (int j = 0; j < 16; ++j) bufB[j] = cb4[(k + 1) * 16 + j];
        cnB = cnorm[k + 1];
        SCORE_UPDATE(bufA, cnA, k)
        // prefetch code k+2 while code k+1 computes
        if (k + 2 < NK) {
            #pragma unroll
            for (int j = 0; j < 16; ++j) bufA[j] = cb4[(k + 2) * 16 + j];
            cnA = cnorm[k + 2];
        }
        SCORE_UPDATE(bufB, cnB, k + 1)
    }
#undef SCORE_UPDATE

    // Exact refinement. gap3 >= MARGIN guarantees the true (fp64) argmin is
    // one of {bidx, b2idx}; compare those exactly. gap3 < MARGIN: full rescan
    // (probability ~0 on this dataset, kept for provable correctness).
    if (best3 - best < MARGIN) {
        double dbest = 1.0e300;
        int di = 0;
        for (int k = 0; k < NK; ++k) {
            double d = dist2_f64(zreg, cb4 + (size_t)k * 16);
            if (d < dbest) { dbest = d; di = k; }
        }
        bidx = di;
    } else if (best2 - best < MARGIN) {
        double da = dist2_f64(zreg, cb4 + (size_t)bidx * 16);
        double db = dist2_f64(zreg, cb4 + (size_t)b2idx * 16);
        if (db < da || (db == da && b2idx < bidx)) bidx = b2idx;  // tie: lowest index
    }

    // Gather winning code row -> z_q, accumulate squared error for the loss.
    float sse = 0.0f;
    const float4* __restrict__ e4 = cb4 + (size_t)bidx * 16;
    #pragma unroll
    for (int j = 0; j < 16; ++j) {
        float4 q = e4[j];
        zq[base + (size_t)(4 * j + 0) * HW] = q.x;
        zq[base + (size_t)(4 * j + 1) * HW] = q.y;
        zq[base + (size_t)(4 * j + 2) * HW] = q.z;
        zq[base + (size_t)(4 * j + 3) * HW] = q.w;
        float t0 = q.x - zreg[4 * j + 0];
        float t1 = q.y - zreg[4 * j + 1];
        float t2 = q.z - zreg[4 * j + 2];
        float t3 = q.w - zreg[4 * j + 3];
        sse = fmaf(t0, t0, sse);
        sse = fmaf(t1, t1, sse);
        sse = fmaf(t2, t2, sse);
        sse = fmaf(t3, t3, sse);
    }

    // Block reduction of sse -> one atomicAdd per block.
    __shared__ float red[4];
    #pragma unroll
    for (int off = 32; off > 0; off >>= 1)
        sse += __shfl_down(sse, off);               // 64-lane wave reduce
    const int lane = threadIdx.x & 63;
    const int wid  = threadIdx.x >> 6;
    if (lane == 0) red[wid] = sse;
    __syncthreads();
    if (threadIdx.x == 0) {
        float bs = red[0] + red[1] + red[2] + red[3];
        // loss = (1 + BETA) * SSE / TOTAL, BETA = 0.25
        atomicAdd(loss_out, bs * (1.25f / (float)TOTAL));
    }
}

extern "C" void kernel_launch(void* const* d_in, const int* in_sizes, int n_in,
                              void* d_out, int out_size, void* d_ws, size_t ws_size,
                              hipStream_t stream) {
    const float* z  = (const float*)d_in[0];   // [32, 64, 64, 64] fp32
    const float* cb = (const float*)d_in[1];   // [1024, 64] fp32
    float* out      = (float*)d_out;           // z_q (8388608 floats) ++ loss (1 float)
    float* zq       = out;
    float* loss_out = out + TOTAL;
    float* cnorm    = (float*)d_ws;            // 1024 floats of scratch

    vq_cnorm_kernel<<<(NK + 255) / 256, 256, 0, stream>>>(cb, cnorm, loss_out);
    vq_argmin_kernel<<<NPIX / 256, 256, 0, stream>>>(z, cb, cnorm, zq, loss_out);
}

// Round 4
// 354.564 us; speedup vs baseline: 8.0053x; 2.6077x over previous
//
#include <hip/hip_runtime.h>
#include <float.h>

#define HW    4096      // H*W
#define NC    64        // channels / latent dim
#define NK    1024      // codebook entries
#define NB    32        // batch
#define NPIX  (NB*HW)   // 131072 pixels
#define TOTAL (NPIX*NC) // 8388608 output elements of z_q

// bf16 hi/lo split score error bound: <= ~4*2^-18 * sum|z_k e_k| ~ 1.4e-3
// worst case on this data. MARGIN 8e-3 gives >4x safety; flagged pixels get
// exact fp64 refinement.
#define MARGIN 8e-3f

typedef __attribute__((ext_vector_type(8))) short short8;   // 8 bf16 (4 VGPRs)
typedef __attribute__((ext_vector_type(4))) float floatx4;  // MFMA acc

__device__ __forceinline__ unsigned short f2bf(float f) {   // fp32 -> bf16 RNE
    unsigned u = __float_as_uint(f);
    u += 0x7FFFu + ((u >> 16) & 1u);
    return (unsigned short)(u >> 16);
}
__device__ __forceinline__ float bf2f(unsigned short h) {
    return __uint_as_float(((unsigned)h) << 16);
}

// top-3 insert, strict < (in-loop: k strictly increasing, ties keep earlier)
__device__ __forceinline__ void ins3f(float& b1, int& i1, float& b2, int& i2,
                                      float& b3, float s, int k) {
    bool lt1 = s < b1;
    bool lt2 = s < b2;
    bool lt3 = s < b3;
    b3 = lt2 ? b2 : (lt3 ? s : b3);
    b2 = lt1 ? b1 : (lt2 ? s : b2);
    i2 = lt1 ? i1 : (lt2 ? k : i2);
    b1 = lt1 ? s : b1;
    i1 = lt1 ? k : i1;
}
// tie-aware version (cross-lane merge: lower index wins on equal score)
__device__ __forceinline__ void ins3t(float& b1, int& i1, float& b2, int& i2,
                                      float& b3, float s, int k) {
    bool lt1 = (s < b1) || (s == b1 && k < i1);
    bool lt2 = (s < b2) || (s == b2 && k < i2);
    bool lt3 = s < b3;
    b3 = lt2 ? b2 : (lt3 ? s : b3);
    b2 = lt1 ? b1 : (lt2 ? s : b2);
    i2 = lt1 ? i1 : (lt2 ? k : i2);
    b1 = lt1 ? s : b1;
    i1 = lt1 ? k : i1;
}

// Prologue: cnorm (fp64-accurate), bf16 hi/lo codebook splits, zero loss.
__global__ void vq_prep_kernel(const float* __restrict__ cb,
                               float* __restrict__ cnorm,
                               unsigned short* __restrict__ cb_hi,
                               unsigned short* __restrict__ cb_lo,
                               float* __restrict__ loss_out) {
    int k = blockIdx.x * 256 + threadIdx.x;
    if (k == 0) loss_out[0] = 0.0f;
    if (k < NK) {
        double s = 0.0;
        #pragma unroll 4
        for (int c = 0; c < NC; ++c) {
            float f = cb[k * NC + c];
            unsigned short h = f2bf(f);
            unsigned short l = f2bf(f - bf2f(h));
            cb_hi[k * NC + c] = h;
            cb_lo[k * NC + c] = l;
            double v = (double)f;
            s = fma(v, v, s);
        }
        cnorm[k] = (float)s;
    }
}

// Main: block = 256 threads / 4 waves / 64 pixels. Each wave scores its 16
// pixels (B operand) against all 1024 codes (A operand, 64 tiles of 16) with
// split-bf16 MFMA; per-lane top-3 + cross-lane merge certifies the argmin;
// ambiguous pixels get exact fp64 refinement.
__global__ __launch_bounds__(256, 4) void vq_mfma_kernel(
        const float* __restrict__ z,
        const float* __restrict__ cb,
        const unsigned short* __restrict__ cb_hi,
        const unsigned short* __restrict__ cb_lo,
        const float* __restrict__ cnorm,
        float* __restrict__ zq,
        float* __restrict__ loss_out) {
    __shared__ unsigned short zh[64][68];   // [ch][px], pad 64->68 (8B-aligned rows)
    __shared__ unsigned short zl[64][68];
    __shared__ float cn_lds[NK];
    __shared__ float rb1[64], rb2[64], rb3[64];
    __shared__ int   ri1[64], ri2[64];
    __shared__ int   finidx[64];
    __shared__ int   flags[64];
    __shared__ double red_s[256];
    __shared__ int    red_i[256];
    __shared__ float  redf[4];

    const int tid = threadIdx.x;
    const int g0  = blockIdx.x * 64;        // first pixel of block
    const int bb  = g0 >> 12;               // batch (64 | 4096 -> uniform)
    const int pp0 = g0 & 4095;
    const float* zbase = z  + (size_t)bb * (NC * HW) + pp0;
    float*      zqbase = zq + (size_t)bb * (NC * HW) + pp0;

    // ---- stage cnorm -> LDS (256 x float4 = 1024) ----
    ((float4*)cn_lds)[tid] = ((const float4*)cnorm)[tid];

    // ---- stage z -> bf16 hi/lo in LDS, layout [ch][px] ----
    {
        const int px4 = (tid & 15) * 4;
        const int c0  = tid >> 4;           // 0..15
        #pragma unroll
        for (int j = 0; j < 4; ++j) {
            const int c = c0 + 16 * j;
            float4 v = *(const float4*)(zbase + (size_t)c * HW + px4);
            unsigned short h0 = f2bf(v.x), h1 = f2bf(v.y),
                           h2 = f2bf(v.z), h3 = f2bf(v.w);
            unsigned short l0 = f2bf(v.x - bf2f(h0)), l1 = f2bf(v.y - bf2f(h1)),
                           l2 = f2bf(v.z - bf2f(h2)), l3 = f2bf(v.w - bf2f(h3));
            uint2 ph = make_uint2((unsigned)h0 | ((unsigned)h1 << 16),
                                  (unsigned)h2 | ((unsigned)h3 << 16));
            uint2 pl = make_uint2((unsigned)l0 | ((unsigned)l1 << 16),
                                  (unsigned)l2 | ((unsigned)l3 << 16));
            *(uint2*)&zh[c][px4] = ph;
            *(uint2*)&zl[c][px4] = pl;
        }
    }
    __syncthreads();

    // ---- hoisted B-operand fragments: B[k][n], n=lane&15, k=quad*8+j ----
    const int lane    = tid & 63;
    const int w       = tid >> 6;
    const int q       = lane >> 4;
    const int pcol    = lane & 15;
    const int ppix    = w * 16 + pcol;      // this lane's pixel (B column)

    short8 bh0, bh1, bl0, bl1;              // [kstep 0/1] x [hi/lo]
    #pragma unroll
    for (int j = 0; j < 8; ++j) {
        const int chA = q * 8 + j;          // k-step 0: ch 0..31
        const int chB = 32 + q * 8 + j;     // k-step 1: ch 32..63
        bh0[j] = (short)zh[chA][ppix];
        bh1[j] = (short)zh[chB][ppix];
        bl0[j] = (short)zl[chA][ppix];
        bl1[j] = (short)zl[chB][ppix];
    }

    // ---- sweep 64 code tiles ----
    const short8* cbh8 = (const short8*)cb_hi;  // row r chunk t*4+q at [r*8 + t*4 + q]
    const short8* cbl8 = (const short8*)cb_lo;

    float b1v = FLT_MAX, b2v = FLT_MAX, b3v = FLT_MAX;
    int i1 = 0, i2 = 0;

    int r0 = pcol;                           // tile 0, A row m = lane&15
    short8 nah0 = cbh8[r0 * 8 + q];
    short8 nah1 = cbh8[r0 * 8 + 4 + q];
    short8 nal0 = cbl8[r0 * 8 + q];
    short8 nal1 = cbl8[r0 * 8 + 4 + q];

    #pragma unroll 2
    for (int tile = 0; tile < 64; ++tile) {
        short8 ah0 = nah0, ah1 = nah1, al0 = nal0, al1 = nal1;
        if (tile < 63) {                     // prefetch next tile's A-frags
            const int r = (tile + 1) * 16 + pcol;
            nah0 = cbh8[r * 8 + q];
            nah1 = cbh8[r * 8 + 4 + q];
            nal0 = cbl8[r * 8 + q];
            nal1 = cbl8[r * 8 + 4 + q];
        }
        floatx4 acc0 = {0.f, 0.f, 0.f, 0.f};
        floatx4 acc1 = {0.f, 0.f, 0.f, 0.f};
        // dot = zh*eh + zl*eh + zh*el  (zl*el dropped, ~2^-18 relative)
        acc0 = __builtin_amdgcn_mfma_f32_16x16x32_bf16(ah0, bh0, acc0, 0, 0, 0);
        acc1 = __builtin_amdgcn_mfma_f32_16x16x32_bf16(ah1, bh1, acc1, 0, 0, 0);
        acc0 = __builtin_amdgcn_mfma_f32_16x16x32_bf16(ah0, bl0, acc0, 0, 0, 0);
        acc1 = __builtin_amdgcn_mfma_f32_16x16x32_bf16(ah1, bl1, acc1, 0, 0, 0);
        acc0 = __builtin_amdgcn_mfma_f32_16x16x32_bf16(al0, bh0, acc0, 0, 0, 0);
        acc1 = __builtin_amdgcn_mfma_f32_16x16x32_bf16(al1, bh1, acc1, 0, 0, 0);

        // C/D layout: code row = q*4 + reg, pixel col = lane&15 (verified m89/m91)
        const float4 cn4 = *(const float4*)&cn_lds[tile * 16 + q * 4];
        const int kb = tile * 16 + q * 4;
        float s0 = fmaf(-2.f, acc0[0] + acc1[0], cn4.x);
        float s1 = fmaf(-2.f, acc0[1] + acc1[1], cn4.y);
        float s2 = fmaf(-2.f, acc0[2] + acc1[2], cn4.z);
        float s3 = fmaf(-2.f, acc0[3] + acc1[3], cn4.w);
        ins3f(b1v, i1, b2v, i2, b3v, s0, kb + 0);
        ins3f(b1v, i1, b2v, i2, b3v, s1, kb + 1);
        ins3f(b1v, i1, b2v, i2, b3v, s2, kb + 2);
        ins3f(b1v, i1, b2v, i2, b3v, s3, kb + 3);
    }

    // ---- merge top-3 across the 4 lanes sharing a pixel (xor 16, 32) ----
    #pragma unroll
    for (int d = 16; d <= 32; d <<= 1) {
        float ob1 = __shfl_xor(b1v, d);
        int   oi1 = __shfl_xor(i1, d);
        float ob2 = __shfl_xor(b2v, d);
        int   oi2 = __shfl_xor(i2, d);
        float ob3 = __shfl_xor(b3v, d);
        ins3t(b1v, i1, b2v, i2, b3v, ob1, oi1);
        ins3t(b1v, i1, b2v, i2, b3v, ob2, oi2);
        b3v = fminf(b3v, ob3);  // other's b3 can at best land in merged rank 3
    }
    if (q == 0) {
        rb1[ppix] = b1v; rb2[ppix] = b2v; rb3[ppix] = b3v;
        ri1[ppix] = i1;  ri2[ppix] = i2;
    }
    __syncthreads();

    // ---- per-pixel decision: certified / fp64 top-2 refine / full rescan ----
    if (tid < 64) {
        flags[tid] = 0;
        int fi = ri1[tid];
        const float g3 = rb3[tid] - rb1[tid];
        const float g2 = rb2[tid] - rb1[tid];
        if (g3 < MARGIN) {
            flags[tid] = 1;                  // needs cooperative full rescan
        } else if (g2 < MARGIN) {
            // true argmin is provably in {ri1, ri2}: exact fp64 compare
            const float* zp = zbase + tid;
            const int ia = fi, ib = ri2[tid];
            const float* ra  = cb + (size_t)ia * NC;
            const float* rbp = cb + (size_t)ib * NC;
            double sa = 0.0, sb = 0.0;
            for (int c = 0; c < NC; ++c) {
                double zv = (double)zp[(size_t)c * HW];
                double ta = zv - (double)ra[c];
                double tb = zv - (double)rbp[c];
                sa = fma(ta, ta, sa);
                sb = fma(tb, tb, sb);
            }
            if (sb < sa || (sb == sa && ib < ia)) fi = ib;
        }
        finidx[tid] = fi;
    }
    __syncthreads();

    // ---- rare (~1e-6/pixel) cooperative exact rescan, block-uniform branch ----
    for (int p = 0; p < 64; ++p) {
        if (flags[p]) {
            const float* zp = zbase + p;
            double bd = 1.0e300; int bi = 0;
            for (int r = 0; r < 4; ++r) {
                const int k = (tid << 2) + r;
                const float* rowp = cb + (size_t)k * NC;
                double s = 0.0;
                for (int c = 0; c < NC; ++c) {
                    double t = (double)zp[(size_t)c * HW] - (double)rowp[c];
                    s = fma(t, t, s);
                }
                if (s < bd || (s == bd && k < bi)) { bd = s; bi = k; }
            }
            red_s[tid] = bd; red_i[tid] = bi;
            __syncthreads();
            if (tid == 0) {
                double m = red_s[0]; int mi = red_i[0];
                for (int t = 1; t < 256; ++t)
                    if (red_s[t] < m || (red_s[t] == m && red_i[t] < mi)) {
                        m = red_s[t]; mi = red_i[t];
                    }
                finidx[p] = mi;
            }
            __syncthreads();
        }
    }

    // ---- epilogue: gather exact fp32 code rows -> z_q, loss SSE ----
    const int p  = tid & 63;
    const int qq = tid >> 6;
    const int fi = finidx[p];
    const float* crow = cb + (size_t)fi * NC;
    float sse = 0.f;
    #pragma unroll
    for (int j = 0; j < 16; ++j) {
        const int c = qq * 16 + j;
        const float qv = crow[c];
        const float zv = zbase[(size_t)c * HW + p];
        zqbase[(size_t)c * HW + p] = qv;     // lanes span p=0..63: coalesced 256B
        const float dd = qv - zv;
        sse = fmaf(dd, dd, sse);
    }
    #pragma unroll
    for (int off = 32; off > 0; off >>= 1) sse += __shfl_down(sse, off);
    if ((tid & 63) == 0) redf[tid >> 6] = sse;
    __syncthreads();
    if (tid == 0)
        atomicAdd(loss_out,
                  (redf[0] + redf[1] + redf[2] + redf[3]) * (1.25f / (float)TOTAL));
}

extern "C" void kernel_launch(void* const* d_in, const int* in_sizes, int n_in,
                              void* d_out, int out_size, void* d_ws, size_t ws_size,
                              hipStream_t stream) {
    const float* z  = (const float*)d_in[0];   // [32, 64, 64, 64] fp32
    const float* cb = (const float*)d_in[1];   // [1024, 64] fp32
    float* out      = (float*)d_out;           // z_q ++ loss
    float* zqp      = out;
    float* loss     = out + TOTAL;

    // workspace layout: cnorm fp32[1024] | cb_hi bf16[1024*64] | cb_lo bf16[1024*64]
    float* cnorm          = (float*)d_ws;
    unsigned short* cb_hi = (unsigned short*)((char*)d_ws + 4096);
    unsigned short* cb_lo = (unsigned short*)((char*)d_ws + 4096 + NK * NC * 2);

    vq_prep_kernel<<<4, 256, 0, stream>>>(cb, cnorm, cb_hi, cb_lo, loss);
    vq_mfma_kernel<<<NPIX / 64, 256, 0, stream>>>(z, cb, cb_hi, cb_lo, cnorm,
                                                  zqp, loss);
}

// Round 5
// 197.391 us; speedup vs baseline: 14.3795x; 1.7962x over previous
//
#include <hip/hip_runtime.h>
#include <float.h>

#define HW    4096      // H*W
#define NC    64        // channels / latent dim
#define NK    1024      // codebook entries
#define NB    32        // batch
#define NPIX  (NB*HW)   // 131072 pixels
#define TOTAL (NPIX*NC) // 8388608 output elements of z_q
#define PPB   256       // pixels per block (64 per wave)

// bf16 hi/lo split score error bound ~1.4e-3 worst case; MARGIN 8e-3 gives
// >4x safety. gap2<MARGIN -> exact fp64 top-2 compare; gap3<MARGIN (rare,
// ~3e-5/pixel) -> cooperative exact fp64 full rescan.
#define MARGIN 8e-3f

typedef __attribute__((ext_vector_type(8))) short short8;   // 8 bf16 (4 VGPRs)
typedef __attribute__((ext_vector_type(4))) float floatx4;  // MFMA acc

__device__ __forceinline__ unsigned short f2bf(float f) {   // fp32 -> bf16 RNE
    unsigned u = __float_as_uint(f);
    u += 0x7FFFu + ((u >> 16) & 1u);
    return (unsigned short)(u >> 16);
}
__device__ __forceinline__ float bf2f(unsigned short h) {
    return __uint_as_float(((unsigned)h) << 16);
}

// top-3 insert, strict < (in-loop: k strictly increasing, ties keep earlier)
__device__ __forceinline__ void ins3f(float& b1, int& i1, float& b2, int& i2,
                                      float& b3, float s, int k) {
    bool lt1 = s < b1;
    bool lt2 = s < b2;
    bool lt3 = s < b3;
    b3 = lt2 ? b2 : (lt3 ? s : b3);
    b2 = lt1 ? b1 : (lt2 ? s : b2);
    i2 = lt1 ? i1 : (lt2 ? k : i2);
    b1 = lt1 ? s : b1;
    i1 = lt1 ? k : i1;
}
// tie-aware version (cross-lane merge: lower index wins on equal score)
__device__ __forceinline__ void ins3t(float& b1, int& i1, float& b2, int& i2,
                                      float& b3, float s, int k) {
    bool lt1 = (s < b1) || (s == b1 && k < i1);
    bool lt2 = (s < b2) || (s == b2 && k < i2);
    bool lt3 = s < b3;
    b3 = lt2 ? b2 : (lt3 ? s : b3);
    b2 = lt1 ? b1 : (lt2 ? s : b2);
    i2 = lt1 ? i1 : (lt2 ? k : i2);
    b1 = lt1 ? s : b1;
    i1 = lt1 ? k : i1;
}

// Prologue: cnorm (fp64-accurate), bf16 hi/lo codebook splits, zero loss.
__global__ void vq_prep_kernel(const float* __restrict__ cb,
                               float* __restrict__ cnorm,
                               unsigned short* __restrict__ cb_hi,
                               unsigned short* __restrict__ cb_lo,
                               float* __restrict__ loss_out) {
    int k = blockIdx.x * 256 + threadIdx.x;
    if (k == 0) loss_out[0] = 0.0f;
    if (k < NK) {
        double s = 0.0;
        #pragma unroll 4
        for (int c = 0; c < NC; ++c) {
            float f = cb[k * NC + c];
            unsigned short h = f2bf(f);
            unsigned short l = f2bf(f - bf2f(h));
            cb_hi[k * NC + c] = h;
            cb_lo[k * NC + c] = l;
            double v = (double)f;
            s = fma(v, v, s);
        }
        cnorm[k] = (float)s;
    }
}

// Main: block = 256 threads / 4 waves / 256 pixels (64 per wave, 4 B-sets).
// Each wave scores 64 pixels against all 1024 codes with split-bf16 MFMA;
// the 4 A-fragment loads per tile are amortized over 24 MFMA, double-buffered
// in registers (launch_bounds(256,2) -> 256-VGPR budget keeps them live).
__global__ __launch_bounds__(256, 2) void vq_mfma_kernel(
        const float* __restrict__ z,
        const float* __restrict__ cb,
        const unsigned short* __restrict__ cb_hi,
        const unsigned short* __restrict__ cb_lo,
        const float* __restrict__ cnorm,
        float* __restrict__ zq,
        float* __restrict__ loss_out) {
    __shared__ unsigned short zh[64][PPB];   // [ch][px] bf16-hi of z (32 KB)
    __shared__ unsigned short zl[64][PPB];   // bf16-lo (32 KB)
    __shared__ alignas(16) float cn_lds[NK]; // 4 KB; aliased by rescan scratch
    __shared__ float rb1[PPB], rb2[PPB], rb3[PPB];
    __shared__ int   ri1[PPB], ri2[PPB];
    __shared__ int   finidx[PPB];
    __shared__ int   flags[PPB];
    __shared__ float redf[4];

    const int tid = threadIdx.x;
    const int g0  = blockIdx.x * PPB;        // first pixel of block
    const int bb  = g0 >> 12;                // batch (256 | 4096 -> uniform)
    const int pp0 = g0 & 4095;
    const float* zbase = z  + (size_t)bb * (NC * HW) + pp0;
    float*      zqbase = zq + (size_t)bb * (NC * HW) + pp0;

    // ---- stage cnorm -> LDS ----
    ((float4*)cn_lds)[tid] = ((const float4*)cnorm)[tid];

    // ---- stage z -> bf16 hi/lo in LDS, layout [ch][px] ----
    {
        const int px4 = (tid & 63) * 4;
        const int c0  = tid >> 6;            // 0..3
        #pragma unroll
        for (int it = 0; it < 16; ++it) {
            const int c = it * 4 + c0;
            float4 v = *(const float4*)(zbase + (size_t)c * HW + px4);
            unsigned short h0 = f2bf(v.x), h1 = f2bf(v.y),
                           h2 = f2bf(v.z), h3 = f2bf(v.w);
            unsigned short l0 = f2bf(v.x - bf2f(h0)), l1 = f2bf(v.y - bf2f(h1)),
                           l2 = f2bf(v.z - bf2f(h2)), l3 = f2bf(v.w - bf2f(h3));
            uint2 ph = make_uint2((unsigned)h0 | ((unsigned)h1 << 16),
                                  (unsigned)h2 | ((unsigned)h3 << 16));
            uint2 pl = make_uint2((unsigned)l0 | ((unsigned)l1 << 16),
                                  (unsigned)l2 | ((unsigned)l3 << 16));
            *(uint2*)&zh[c][px4] = ph;
            *(uint2*)&zl[c][px4] = pl;
        }
    }
    __syncthreads();

    // ---- hoisted B fragments: 4 pixel sets per wave ----
    const int lane = tid & 63;
    const int w    = tid >> 6;
    const int q    = lane >> 4;
    const int pcol = lane & 15;

    short8 Bh0[4], Bh1[4], Bl0[4], Bl1[4];
    #pragma unroll
    for (int j = 0; j < 4; ++j) {
        const int px = w * 64 + j * 16 + pcol;   // this lane's pixel, set j
        #pragma unroll
        for (int t = 0; t < 8; ++t) {
            Bh0[j][t] = (short)zh[q * 8 + t][px];
            Bh1[j][t] = (short)zh[32 + q * 8 + t][px];
            Bl0[j][t] = (short)zl[q * 8 + t][px];
            Bl1[j][t] = (short)zl[32 + q * 8 + t][px];
        }
    }

    // ---- sweep 64 code tiles, A fragments double-buffered in registers ----
    const short8* cbh8 = (const short8*)cb_hi;
    const short8* cbl8 = (const short8*)cb_lo;

    float B1[4], B2[4], B3[4];
    int   I1[4], I2[4];
    #pragma unroll
    for (int j = 0; j < 4; ++j) {
        B1[j] = FLT_MAX; B2[j] = FLT_MAX; B3[j] = FLT_MAX;
        I1[j] = 0; I2[j] = 0;
    }

    short8 nah0 = cbh8[pcol * 8 + q];
    short8 nah1 = cbh8[pcol * 8 + 4 + q];
    short8 nal0 = cbl8[pcol * 8 + q];
    short8 nal1 = cbl8[pcol * 8 + 4 + q];

    #pragma unroll 2
    for (int tile = 0; tile < 64; ++tile) {
        short8 ah0 = nah0, ah1 = nah1, al0 = nal0, al1 = nal1;
        if (tile < 63) {                     // prefetch next tile's A frags
            const int r = (tile + 1) * 16 + pcol;
            nah0 = cbh8[r * 8 + q];
            nah1 = cbh8[r * 8 + 4 + q];
            nal0 = cbl8[r * 8 + q];
            nal1 = cbl8[r * 8 + 4 + q];
        }
        const float4 cn4 = *(const float4*)&cn_lds[tile * 16 + q * 4];
        const int kb = tile * 16 + q * 4;
        #pragma unroll
        for (int j = 0; j < 4; ++j) {
            floatx4 a0 = {0.f, 0.f, 0.f, 0.f};
            floatx4 a1 = {0.f, 0.f, 0.f, 0.f};
            // dot = zh*eh + zh*el + zl*eh (zl*el dropped, ~2^-18 relative)
            a0 = __builtin_amdgcn_mfma_f32_16x16x32_bf16(ah0, Bh0[j], a0, 0, 0, 0);
            a1 = __builtin_amdgcn_mfma_f32_16x16x32_bf16(ah1, Bh1[j], a1, 0, 0, 0);
            a0 = __builtin_amdgcn_mfma_f32_16x16x32_bf16(ah0, Bl0[j], a0, 0, 0, 0);
            a1 = __builtin_amdgcn_mfma_f32_16x16x32_bf16(ah1, Bl1[j], a1, 0, 0, 0);
            a0 = __builtin_amdgcn_mfma_f32_16x16x32_bf16(al0, Bh0[j], a0, 0, 0, 0);
            a1 = __builtin_amdgcn_mfma_f32_16x16x32_bf16(al1, Bh1[j], a1, 0, 0, 0);

            // C/D layout: code row = q*4+reg, pixel col = lane&15 (verified)
            float s0 = fmaf(-2.f, a0[0] + a1[0], cn4.x);
            float s1 = fmaf(-2.f, a0[1] + a1[1], cn4.y);
            float s2 = fmaf(-2.f, a0[2] + a1[2], cn4.z);
            float s3 = fmaf(-2.f, a0[3] + a1[3], cn4.w);
            ins3f(B1[j], I1[j], B2[j], I2[j], B3[j], s0, kb + 0);
            ins3f(B1[j], I1[j], B2[j], I2[j], B3[j], s1, kb + 1);
            ins3f(B1[j], I1[j], B2[j], I2[j], B3[j], s2, kb + 2);
            ins3f(B1[j], I1[j], B2[j], I2[j], B3[j], s3, kb + 3);
        }
    }

    // ---- merge top-3 across the 4 lanes sharing each pixel (xor 16,32) ----
    #pragma unroll
    for (int j = 0; j < 4; ++j) {
        float b1v = B1[j], b2v = B2[j], b3v = B3[j];
        int i1 = I1[j], i2 = I2[j];
        #pragma unroll
        for (int d = 16; d <= 32; d <<= 1) {
            float ob1 = __shfl_xor(b1v, d);
            int   oi1 = __shfl_xor(i1, d);
            float ob2 = __shfl_xor(b2v, d);
            int   oi2 = __shfl_xor(i2, d);
            float ob3 = __shfl_xor(b3v, d);
            ins3t(b1v, i1, b2v, i2, b3v, ob1, oi1);
            ins3t(b1v, i1, b2v, i2, b3v, ob2, oi2);
            b3v = fminf(b3v, ob3);
        }
        if (q == 0) {
            const int px = w * 64 + j * 16 + pcol;
            rb1[px] = b1v; rb2[px] = b2v; rb3[px] = b3v;
            ri1[px] = i1;  ri2[px] = i2;
        }
    }
    __syncthreads();

    // ---- per-pixel decision (1 thread per pixel) ----
    int flag = 0;
    {
        const int p = tid;
        int fi = ri1[p];
        const float g3 = rb3[p] - rb1[p];
        const float g2 = rb2[p] - rb1[p];
        if (g3 < MARGIN) {
            flag = 1;                        // needs cooperative full rescan
        } else if (g2 < MARGIN) {
            // true argmin provably in {ri1, ri2}: exact fp64 compare
            const float* zp = zbase + p;
            const int ia = fi, ib = ri2[p];
            const float* ra  = cb + (size_t)ia * NC;
            const float* rbp = cb + (size_t)ib * NC;
            double sa = 0.0, sb = 0.0;
            for (int c = 0; c < NC; ++c) {
                double zv = (double)zp[(size_t)c * HW];
                double ta = zv - (double)ra[c];
                double tb = zv - (double)rbp[c];
                sa = fma(ta, ta, sa);
                sb = fma(tb, tb, sb);
            }
            if (sb < sa || (sb == sa && ib < ia)) fi = ib;
        }
        finidx[p] = fi;
        flags[p]  = flag;
    }
    const int nflag = __syncthreads_count(flag);

    // ---- rare cooperative exact rescan (scratch aliases cn_lds) ----
    if (nflag > 0) {
        double* red_s = reinterpret_cast<double*>(cn_lds);       // 2 KB
        int*    red_i = reinterpret_cast<int*>(cn_lds + 512);    // 1 KB
        for (int p = 0; p < PPB; ++p) {
            if (flags[p]) {
                const float* zp = zbase + p;
                double bd = 1.0e300; int bi = 0;
                #pragma unroll 1
                for (int r = 0; r < 4; ++r) {
                    const int k = tid * 4 + r;
                    const float* rowp = cb + (size_t)k * NC;
                    double s = 0.0;
                    for (int c = 0; c < NC; ++c) {
                        double t = (double)zp[(size_t)c * HW] - (double)rowp[c];
                        s = fma(t, t, s);
                    }
                    if (s < bd) { bd = s; bi = k; }  // k increasing: first min
                }
                red_s[tid] = bd; red_i[tid] = bi;
                __syncthreads();
                if (tid < 64) {
                    double m = red_s[tid]; int mi = red_i[tid];
                    #pragma unroll
                    for (int t = 1; t < 4; ++t) {
                        double om = red_s[tid + 64 * t];
                        int    oi = red_i[tid + 64 * t];
                        if (om < m || (om == m && oi < mi)) { m = om; mi = oi; }
                    }
                    #pragma unroll
                    for (int off = 32; off > 0; off >>= 1) {
                        double om = __shfl_down(m, off);
                        int    oi = __shfl_down(mi, off);
                        if (om < m || (om == m && oi < mi)) { m = om; mi = oi; }
                    }
                    if (tid == 0) finidx[p] = mi;
                }
                __syncthreads();
            }
        }
        __syncthreads();
    }

    // ---- epilogue: gather exact fp32 code row -> z_q, loss SSE ----
    {
        const int p  = tid;
        const int fi = finidx[p];
        const float4* crow4 = (const float4*)(cb + (size_t)fi * NC);
        float sse = 0.f;
        #pragma unroll
        for (int j = 0; j < 16; ++j) {
            const float4 qv = crow4[j];
            const size_t c0 = (size_t)(4 * j) * HW + p;
            const float z0 = zbase[c0];
            const float z1 = zbase[c0 + HW];
            const float z2 = zbase[c0 + 2 * (size_t)HW];
            const float z3 = zbase[c0 + 3 * (size_t)HW];
            zqbase[c0]                  = qv.x;   // coalesced across threads
            zqbase[c0 + HW]             = qv.y;
            zqbase[c0 + 2 * (size_t)HW] = qv.z;
            zqbase[c0 + 3 * (size_t)HW] = qv.w;
            float t0 = qv.x - z0, t1 = qv.y - z1, t2 = qv.z - z2, t3 = qv.w - z3;
            sse = fmaf(t0, t0, sse);
            sse = fmaf(t1, t1, sse);
            sse = fmaf(t2, t2, sse);
            sse = fmaf(t3, t3, sse);
        }
        #pragma unroll
        for (int off = 32; off > 0; off >>= 1) sse += __shfl_down(sse, off);
        if ((tid & 63) == 0) redf[tid >> 6] = sse;
        __syncthreads();
        if (tid == 0)
            atomicAdd(loss_out, (redf[0] + redf[1] + redf[2] + redf[3]) *
                                (1.25f / (float)TOTAL));
    }
}

extern "C" void kernel_launch(void* const* d_in, const int* in_sizes, int n_in,
                              void* d_out, int out_size, void* d_ws, size_t ws_size,
                              hipStream_t stream) {
    const float* z  = (const float*)d_in[0];   // [32, 64, 64, 64] fp32
    const float* cb = (const float*)d_in[1];   // [1024, 64] fp32
    float* out      = (float*)d_out;           // z_q ++ loss
    float* zqp      = out;
    float* loss     = out + TOTAL;

    // ws: cnorm fp32[1024] | cb_hi bf16[1024*64] | cb_lo bf16[1024*64]
    float* cnorm          = (float*)d_ws;
    unsigned short* cb_hi = (unsigned short*)((char*)d_ws + 4096);
    unsigned short* cb_lo = (unsigned short*)((char*)d_ws + 4096 + NK * NC * 2);

    vq_prep_kernel<<<4, 256, 0, stream>>>(cb, cnorm, cb_hi, cb_lo, loss);
    vq_mfma_kernel<<<NPIX / PPB, 256, 0, stream>>>(z, cb, cb_hi, cb_lo, cnorm,
                                                   zqp, loss);
}